// Round 2
// 358.668 us; speedup vs baseline: 1.0637x; 1.0637x over previous
//
#include <hip/hip_runtime.h>
#include <hip/hip_fp16.h>

#define C 4096
#define NN 110
#define MPAD 112
#define BN 128
#define BK 64
#define KCHUNK 512
#define NIT (KCHUNK / BK)   // 8
#define LDSTR 72            // As stride (f16 elems): 144 B rows -> 16B aligned
#define BSTR 64             // Bs stride (f16 elems): unpadded, XOR-swizzled 16B blocks

typedef _Float16 f16x8 __attribute__((ext_vector_type(8)));
typedef float fx4 __attribute__((ext_vector_type(4)));

// ---------------------------------------------------------------------------
// prep1: A1[112][4096] = fp16(x), rows >=110 zeroed. u32 pair stores.
// ---------------------------------------------------------------------------
__global__ __launch_bounds__(256)
void prep1_kernel(const float* __restrict__ x, _Float16* __restrict__ A1) {
    int idx = blockIdx.x * 256 + threadIdx.x;     // pair index, 112*2048 total
    int n = idx >> 11;                            // 2048 pairs per row
    union { _Float16 h[2]; unsigned u; } pk;
    pk.u = 0;
    if (n < NN) {
        float2 v = *(const float2*)(x + 2 * (size_t)idx);
        pk.h[0] = (_Float16)v.x;
        pk.h[1] = (_Float16)v.y;
    }
    ((unsigned*)A1)[idx] = pk.u;
}

// ---------------------------------------------------------------------------
// mm: Cacc[0:110, :] += A16[0:112, k0:k0+512] @ fp16(B[k0:k0+512, :])
// 2-phase pipeline: issue global loads for chunk t+1 into regs, MFMA chunk t,
// then convert+ds_write t+1 into the other LDS buffer. One barrier per iter.
// ---------------------------------------------------------------------------
__global__ __launch_bounds__(256, 2)
void mm_kernel(const _Float16* __restrict__ A, const float* __restrict__ B,
               float* __restrict__ Cacc, int lda) {
    __shared__ _Float16 As[2][MPAD * LDSTR];   // padded: row*144B, 16B aligned
    __shared__ _Float16 Bs[2][BN * BSTR];      // Bs[col][k], 128B rows + XOR swizzle

    const int t    = threadIdx.x;
    const int j0   = blockIdx.x * BN;
    const int k0   = blockIdx.y * KCHUNK;
    const int w    = t >> 6;
    const int L    = t & 63;
    const int l15  = L & 15;
    const int q    = L >> 4;
    const int bc   = t & 127;     // staging column
    const int bgq  = t >> 7;      // 0..1
    const int bswz = bc & 7;      // write-side swizzle key

    // A staging slots (4 x f16x8 per thread, 896 slots total)
    int arow[4], ako[4];
    bool aval[4];
#pragma unroll
    for (int i = 0; i < 4; ++i) {
        int idx = t + i * 256;
        aval[i] = (idx < MPAD * (BK / 8));      // 896
        int id2 = aval[i] ? idx : 0;
        arow[i] = id2 >> 3;
        ako[i]  = (id2 & 7) << 3;
    }

    fx4 acc[7][2];
#pragma unroll
    for (int mt = 0; mt < 7; ++mt)
#pragma unroll
        for (int nt = 0; nt < 2; ++nt)
            acc[mt][nt] = (fx4){0.f, 0.f, 0.f, 0.f};

    f16x8 av[4];
    float bv[32];

#define STAGE(kc_)                                                             \
    {                                                                          \
        _Pragma("unroll")                                                      \
        for (int i = 0; i < 4; ++i)                                            \
            av[i] = *(const f16x8*)(A + (size_t)arow[i] * lda + (k0 + (kc_)) + ako[i]); \
        _Pragma("unroll")                                                      \
        for (int p = 0; p < 16; ++p) {                                         \
            int r = (bgq * 16 + p) * 2;                                        \
            bv[2 * p]     = B[(size_t)(k0 + (kc_) + r) * C + j0 + bc];         \
            bv[2 * p + 1] = B[(size_t)(k0 + (kc_) + r + 1) * C + j0 + bc];     \
        }                                                                      \
    }

#define COMMIT(b_)                                                             \
    {                                                                          \
        _Pragma("unroll")                                                      \
        for (int i = 0; i < 4; ++i)                                            \
            if (aval[i])                                                       \
                *(f16x8*)(As[b_] + arow[i] * LDSTR + ako[i]) = av[i];          \
        _Pragma("unroll")                                                      \
        for (int p = 0; p < 16; ++p) {                                         \
            int P = bgq * 16 + p;                                              \
            union { _Float16 h[2]; unsigned u; } pk;                           \
            pk.h[0] = (_Float16)bv[2 * p];                                     \
            pk.h[1] = (_Float16)bv[2 * p + 1];                                 \
            *(unsigned*)(Bs[b_] + bc * BSTR + (((P >> 2) ^ bswz) << 3)         \
                         + ((P & 3) << 1)) = pk.u;                             \
        }                                                                      \
    }

    // prologue: fill buffer 0 (one full-latency stall, once)
    STAGE(0);
    COMMIT(0);
    __syncthreads();

    for (int it = 0; it < NIT; ++it) {
        if (it + 1 < NIT) STAGE((it + 1) * BK);   // issue-early (overlaps MFMA)
        const int b = it & 1;
#pragma unroll
        for (int s = 0; s < 2; ++s) {
            const int ko = s * 32 + q * 8;
            f16x8 bfrag[2];
#pragma unroll
            for (int nt = 0; nt < 2; ++nt) {
                const int cW = w * 32 + nt * 16 + l15;
                bfrag[nt] = *(const f16x8*)(Bs[b] + cW * BSTR
                                + ((((s << 2) + q) ^ (l15 & 7)) << 3));
            }
#pragma unroll
            for (int mt = 0; mt < 7; ++mt) {
                f16x8 afrag = *(const f16x8*)(As[b] + (mt * 16 + l15) * LDSTR + ko);
#pragma unroll
                for (int nt = 0; nt < 2; ++nt)
                    acc[mt][nt] = __builtin_amdgcn_mfma_f32_16x16x32_f16(
                        afrag, bfrag[nt], acc[mt][nt], 0, 0, 0);
            }
        }
        if (it + 1 < NIT) COMMIT((it + 1) & 1);   // write-late (auto vmcnt wait)
        __syncthreads();
        // hazard: COMMIT targets buf[(it+1)&1]; its last read was iter it-1's
        // MFMA, separated by the barrier at end of iter it-1 -> 1 barrier safe.
    }

    // epilogue: fp32 atomic accumulate (C/D layout: col=lane&15, row=q*4+reg)
#pragma unroll
    for (int mt = 0; mt < 7; ++mt)
#pragma unroll
        for (int nt = 0; nt < 2; ++nt) {
            const int col = j0 + w * 32 + nt * 16 + l15;
#pragma unroll
            for (int r = 0; r < 4; ++r) {
                int row = mt * 16 + q * 4 + r;
                if (row < NN)
                    atomicAdd(&Cacc[(size_t)row * C + col], acc[mt][nt][r]);
            }
        }
#undef STAGE
#undef COMMIT
}

// ---------------------------------------------------------------------------
// agg: per 16-col tile, builds A3 = fp16([h+b2, aggr]) [112][8192], u32 stores
// ---------------------------------------------------------------------------
__global__ __launch_bounds__(256)
void agg_kernel(const float* __restrict__ h_raw, const int* __restrict__ adj,
                const float* __restrict__ b2, _Float16* __restrict__ A3) {
    __shared__ float hb[NN * 16];
    __shared__ unsigned long long mlo[NN], mhi[NN];
    __shared__ float degs[NN];
    const int t  = threadIdx.x;
    const int c0 = blockIdx.x * 16;

    // load h tile (+bias) as pairs, emit A3 first half
    for (int idx = t; idx < NN * 8; idx += 256) {
        int n = idx >> 3, cp = (idx & 7) << 1;
        float2 v = *(const float2*)(h_raw + (size_t)n * C + c0 + cp);
        float v0 = v.x + b2[c0 + cp];
        float v1 = v.y + b2[c0 + cp + 1];
        hb[n * 16 + cp]     = v0;
        hb[n * 16 + cp + 1] = v1;
        union { _Float16 h[2]; unsigned u; } pk;
        pk.h[0] = (_Float16)v0;
        pk.h[1] = (_Float16)v1;
        *(unsigned*)(A3 + (size_t)n * (2 * C) + c0 + cp) = pk.u;
    }
    // zero pad rows 110,111 (both halves of this c-tile)
    if (t < 32) {
        int n  = NN + (t >> 4);
        int hs = (t >> 3) & 1;
        int cp = (t & 7) << 1;
        *(unsigned*)(A3 + (size_t)n * (2 * C) + hs * C + c0 + cp) = 0u;
    }
    // mask bits + degree per target j
    if (t < NN) {
        int j = t;
        unsigned long long lo = 0, hi = 0;
        int dg = 0;
        for (int i = 0; i < 64; ++i) {
            int m = (adj[i * NN + j] != 0);
            lo |= ((unsigned long long)m) << i; dg += m;
        }
        for (int i = 64; i < NN; ++i) {
            int m = (adj[i * NN + j] != 0);
            hi |= ((unsigned long long)m) << (i - 64); dg += m;
        }
        mlo[j] = lo; mhi[j] = hi;
        degs[j] = (float)(dg > 0 ? dg : 1);
    }
    __syncthreads();
    // aggr -> A3 second half (2 cols per thread-slot)
    for (int idx = t; idx < NN * 8; idx += 256) {
        int j = idx >> 3, cp = (idx & 7) << 1;
        unsigned long long lo = mlo[j], hi = mhi[j];
        float a0 = 0.f, a1 = 0.f;
        for (int i = 0; i < 64; ++i)
            if ((lo >> i) & 1) { a0 += hb[i * 16 + cp]; a1 += hb[i * 16 + cp + 1]; }
        for (int i = 64; i < NN; ++i)
            if ((hi >> (i - 64)) & 1) { a0 += hb[i * 16 + cp]; a1 += hb[i * 16 + cp + 1]; }
        union { _Float16 h[2]; unsigned u; } pk;
        pk.h[0] = (_Float16)(a0 / degs[j]);
        pk.h[1] = (_Float16)(a1 / degs[j]);
        *(unsigned*)(A3 + (size_t)j * (2 * C) + C + c0 + cp) = pk.u;
    }
}

// ---------------------------------------------------------------------------
// fin: out[j,c] = sum_k Wl[j,k] * relu(z_raw[k,c]+b1[c]) + bl[j]
// grid (64 c-tiles, 4 j-slabs); each block reuses its zs stage for 7 j-groups.
// ---------------------------------------------------------------------------
__global__ __launch_bounds__(256)
void fin_kernel(const float* __restrict__ z_raw, const float* __restrict__ b1,
                const float* __restrict__ Wl, const float* __restrict__ bl,
                float* __restrict__ out) {
    __shared__ float zs[NN * 64];
    const int t  = threadIdx.x;
    const int c0 = blockIdx.x * 64;
    const int c  = t & 63;

    for (int idx = t; idx < NN * 64; idx += 256) {
        int k = idx >> 6, cc = idx & 63;
        float v = z_raw[(size_t)k * C + c0 + cc] + b1[c0 + cc];
        zs[idx] = fmaxf(v, 0.f);
    }
    __syncthreads();
    for (int jj = 0; jj < 7; ++jj) {
        int j = blockIdx.y * 28 + jj * 4 + (t >> 6);
        if (j < NN) {
            float a = bl[j];
#pragma unroll 2
            for (int k = 0; k < NN; ++k)
                a += Wl[j * NN + k] * zs[k * 64 + c];   // Wl wave-uniform -> scalar
            out[(size_t)j * C + c0 + c] = a;
        }
    }
}

// ---------------------------------------------------------------------------
extern "C" void kernel_launch(void* const* d_in, const int* in_sizes, int n_in,
                              void* d_out, int out_size, void* d_ws, size_t ws_size,
                              hipStream_t stream) {
    const float* x   = (const float*)d_in[0];
    const int*   adj = (const int*)d_in[1];
    const float* W2  = (const float*)d_in[2];
    const float* b2  = (const float*)d_in[3];
    const float* W1  = (const float*)d_in[4];
    const float* b1  = (const float*)d_in[5];
    const float* Wl  = (const float*)d_in[6];
    const float* bl  = (const float*)d_in[7];
    float* out = (float*)d_out;

    char* ws = (char*)d_ws;
    float*    h_raw = (float*)(ws);                    // 110*4096 f32
    float*    z_raw = (float*)(ws + 1802240);          // 110*4096 f32
    _Float16* A1    = (_Float16*)(ws + 3604480);       // 112*4096 f16
    _Float16* A3    = (_Float16*)(ws + 4521984);       // 112*8192 f16

    hipMemsetAsync(d_ws, 0, 3604480, stream);                           // zero h_raw,z_raw
    prep1_kernel<<<(MPAD * C / 2) / 256, 256, 0, stream>>>(x, A1);      // 896 blocks
    mm_kernel<<<dim3(C / BN, C / KCHUNK), 256, 0, stream>>>(A1, W2, h_raw, C);
    agg_kernel<<<C / 16, 256, 0, stream>>>(h_raw, adj, b2, A3);
    mm_kernel<<<dim3(C / BN, (2 * C) / KCHUNK), 256, 0, stream>>>(A3, W1, z_raw, 2 * C);
    fin_kernel<<<dim3(C / 64, 4), 256, 0, stream>>>(z_raw, b1, Wl, bl, out);
}